// Round 8
// baseline (333.321 us; speedup 1.0000x reference)
//
#include <hip/hip_runtime.h>
#include <hip/hip_bf16.h>

#define N_POINTS   2000000
#define NUM_GRAPHS 16384
#define HID        40
#define SLOPE      0.01f

// Pass A tiling: 512 pts/block, 2 pts/thread
#define TILE_A     512
#define NT_A       ((N_POINTS + TILE_A - 1) / TILE_A)   // 3907
#define XESA       584    // dwords per xeT channel row (chunk-padded max idx 571; %32==8; 16B aligned)

// Pass C tiling: 256 pts/tile, grid-stride
#define TILE       256
#define NTILES     ((N_POINTS + TILE - 1) / TILE)       // 7813
#define AROW       20     // dwords per bf16 A-staging row (40 bf16)
#define XOS        260    // dwords per xoT channel row (%32==4, 16B aligned)
#define GRID_C     1536   // up to 6 blocks/CU (LDS-limited); grid-stride tolerates fewer

typedef __attribute__((ext_vector_type(8))) short short8;
typedef __attribute__((ext_vector_type(4))) float fx4;

__device__ __forceinline__ float lrelu(float v) { return v > 0.f ? v : SLOPE * v; }
__device__ __forceinline__ int padidx(int p) { return p + ((p >> 5) << 2); }  // +4 dwords per 32-chunk
__device__ __forceinline__ unsigned short f2bf(float f) {
    __hip_bfloat16 h = __float2bfloat16(f);
    return *(unsigned short*)&h;
}
__device__ __forceinline__ unsigned int packbf2(float a, float b) {
    __hip_bfloat162 p = __float22bfloat162_rn(make_float2(a, b));
    return *(unsigned int*)&p;
}
__device__ __forceinline__ float bflo(unsigned int d) { return __uint_as_float(d << 16); }
__device__ __forceinline__ float bfhi(unsigned int d) { return __uint_as_float(d & 0xffff0000u); }

// ---------------- Pass A: emb FFN (2 pts/thread) + transpose-reduce + xe bf16 cache ----------------
__global__ __launch_bounds__(256) void k_emb_aggr(
    const float* __restrict__ x, const int* __restrict__ batch,
    const float* __restrict__ We1, const float* __restrict__ We2,
    float* __restrict__ x_aggr, unsigned short* __restrict__ xe_out, int use_xe)
{
    __shared__ __align__(16) float sWe1[3 * HID];
    __shared__ __align__(16) float sWe2T[5 * HID];          // [c][j]
    __shared__ __align__(16) float xeT[5 * XESA];           // chunk-padded
    __shared__ __align__(16) int   sbp[XESA];

    int tid = threadIdx.x;
    for (int k = tid; k < 3 * HID; k += 256) sWe1[k] = We1[k];
    for (int k = tid; k < 5 * HID; k += 256) sWe2T[k] = We2[(k % HID) * 5 + k / HID];
    __syncthreads();

    int base = blockIdx.x * TILE_A;
    int p0 = base + tid, p1 = base + 256 + tid;
    bool v0 = p0 < N_POINTS, v1 = p1 < N_POINTS;
    int i0 = v0 ? p0 : (N_POINTS - 1), i1 = v1 ? p1 : (N_POINTS - 1);
    float a0 = x[i0 * 3 + 0], a1 = x[i0 * 3 + 1], a2 = x[i0 * 3 + 2];
    float c0 = x[i1 * 3 + 0], c1 = x[i1 * 3 + 1], c2 = x[i1 * 3 + 2];
    int b0 = v0 ? batch[i0] : -1;
    int b1 = v1 ? batch[i1] : -1;
    sbp[padidx(tid)] = b0;
    sbp[padidx(256 + tid)] = b1;

    // layer 1: one weight read feeds 2 points
    float h0[HID], h1[HID];
    const float4* W1r = (const float4*)sWe1;
#pragma unroll
    for (int j4 = 0; j4 < HID / 4; ++j4) {
        float4 wa = W1r[j4], wb = W1r[10 + j4], wc = W1r[20 + j4];
        float wav[4] = {wa.x, wa.y, wa.z, wa.w};
        float wbv[4] = {wb.x, wb.y, wb.z, wb.w};
        float wcv[4] = {wc.x, wc.y, wc.z, wc.w};
#pragma unroll
        for (int k = 0; k < 4; ++k) {
            int j = j4 * 4 + k;
            h0[j] = lrelu(a0 * wav[k] + a1 * wbv[k] + a2 * wcv[k]);
            h1[j] = lrelu(c0 * wav[k] + c1 * wbv[k] + c2 * wcv[k]);
        }
    }

    // layer 2 + stage (fp32 into aggregation; bf16 into cache)
    float e0v[5], e1v[5];
#pragma unroll
    for (int c = 0; c < 5; ++c) {
        const float4* wr = (const float4*)&sWe2T[c * HID];
        float s0 = 0.f, s1 = 0.f;
#pragma unroll
        for (int j4 = 0; j4 < HID / 4; ++j4) {
            float4 w = wr[j4];
            float wv[4] = {w.x, w.y, w.z, w.w};
#pragma unroll
            for (int k = 0; k < 4; ++k) {
                s0 += h0[j4 * 4 + k] * wv[k];
                s1 += h1[j4 * 4 + k] * wv[k];
            }
        }
        e0v[c] = v0 ? lrelu(s0) : 0.f;
        e1v[c] = v1 ? lrelu(s1) : 0.f;
        xeT[c * XESA + padidx(tid)] = e0v[c];
        xeT[c * XESA + padidx(256 + tid)] = e1v[c];
    }
    if (use_xe) {
        if (v0) {
            uint4 u;
            u.x = packbf2(e0v[0], e0v[1]); u.y = packbf2(e0v[2], e0v[3]);
            u.z = packbf2(e0v[4], 0.f);    u.w = 0u;
            *(uint4*)&xe_out[(size_t)p0 * 8] = u;
        }
        if (v1) {
            uint4 u;
            u.x = packbf2(e1v[0], e1v[1]); u.y = packbf2(e1v[2], e1v[3]);
            u.z = packbf2(e1v[4], 0.f);    u.w = 0u;
            *(uint4*)&xe_out[(size_t)p1 * 8] = u;
        }
    }
    __syncthreads();

    // reduce: thread tid<80 owns (ch = tid>>4 in 0..4, chunk = tid&15 of 32 pts)
    if (tid < 80) {
        int ch = tid >> 4, chunk = tid & 15;
        float acc = 0.f;
        int cur = sbp[chunk * 36];
#pragma unroll
        for (int g = 0; g < 8; ++g) {
            float4 v4 = *(const float4*)&xeT[ch * XESA + chunk * 36 + g * 4];
            int4   n4 = *(const int4*)&sbp[chunk * 36 + g * 4];
            float vv[4] = {v4.x, v4.y, v4.z, v4.w};
            int   nn[4] = {n4.x, n4.y, n4.z, n4.w};
#pragma unroll
            for (int k = 0; k < 4; ++k) {
                if (nn[k] != cur) {
                    if (cur >= 0) atomicAdd(&x_aggr[cur * 5 + ch], acc);
                    cur = nn[k];
                    acc = vv[k];
                } else {
                    acc += vv[k];
                }
            }
        }
        if (cur >= 0) atomicAdd(&x_aggr[cur * 5 + ch], acc);
    }
}

// ---------------- Pass B: per-graph global FFN + fold into W_out1 rows 5..8 ----------------
__global__ __launch_bounds__(256) void k_global(
    const float* __restrict__ x_aggr,
    const float* __restrict__ Wg1, const float* __restrict__ Wg2,
    const float* __restrict__ Wo1,
    float* __restrict__ g_contrib)
{
    __shared__ float sWg1[5 * HID];
    __shared__ float sWg2[HID * 4];
    __shared__ float sWo1g[4 * HID];
    for (int k = threadIdx.x; k < 5 * HID; k += 256) sWg1[k] = Wg1[k];
    for (int k = threadIdx.x; k < HID * 4; k += 256) sWg2[k] = Wg2[k];
    for (int k = threadIdx.x; k < 4 * HID; k += 256) sWo1g[k] = Wo1[5 * HID + k];
    __syncthreads();

    int bg = blockIdx.x * 256 + threadIdx.x;
    if (bg >= NUM_GRAPHS) return;

    float a[5];
#pragma unroll
    for (int c = 0; c < 5; ++c) a[c] = x_aggr[bg * 5 + c];

    float h[HID];
#pragma unroll
    for (int j = 0; j < HID; ++j) {
        float s = 0.f;
#pragma unroll
        for (int c = 0; c < 5; ++c) s += a[c] * sWg1[c * HID + j];
        h[j] = lrelu(s);
    }
    float g[4];
#pragma unroll
    for (int c = 0; c < 4; ++c) {
        float s = 0.f;
#pragma unroll
        for (int j = 0; j < HID; ++j) s += h[j] * sWg2[j * 4 + c];
        g[c] = lrelu(s);
    }
#pragma unroll
    for (int j = 0; j < HID; ++j) {
        float s = 0.f;
#pragma unroll
        for (int c = 0; c < 4; ++c) s += g[c] * sWo1g[c * HID + j];
        g_contrib[bg * HID + j] = s;
    }
}

// ---------------- Pass C: prefetched xe load, h1 VALU, 40x32 bf16 MFMA, two-half transpose-pool ----------------
// launch_bounds(256,4): R6-proven register budget (VGPR ~64-80, no spill); LDS ~24 KB
// lets HW run up to 6 blocks/CU if VGPR <= 85. R7's (256,6) forced VGPR->40 = 290 MB spill.
__global__ __launch_bounds__(256, 4) void k_out_pool(
    const float* __restrict__ x, const int* __restrict__ batch,
    const float* __restrict__ We1, const float* __restrict__ We2,
    const float* __restrict__ Wo1, const float* __restrict__ Wo2,
    const float* __restrict__ g_contrib,
    const unsigned short* __restrict__ xe_in, int use_xe,
    float* __restrict__ pooled)
{
    // Aliased region: A-staging (256 rows x 20 dw = 20480 B) / xoT half (16 x 260 x 4 = 16640 B)
    __shared__ __align__(16) unsigned int uLds[TILE * AROW];
    __shared__ __align__(16) int sb[TILE];
    __shared__ float sWe1[3 * HID];      // fallback path only
    __shared__ float sWe2T[5 * HID];     // fallback path only
    __shared__ float sWo1[5 * HID];

    int tid = threadIdx.x;
    for (int k = tid; k < 3 * HID; k += 256) sWe1[k] = We1[k];
    for (int k = tid; k < 5 * HID; k += 256) sWe2T[k] = We2[(k % HID) * 5 + k / HID];
    for (int k = tid; k < 5 * HID; k += 256) sWo1[k] = Wo1[k];

    int lane = tid & 63;
    int l16 = lane & 15, quad = lane >> 4;

    // B fragments (Wo2 -> bf16), built once: lane l16 = n, k = ks*32 + quad*8 + j
    short8 bfrag[2][2];
#pragma unroll
    for (int nt = 0; nt < 2; ++nt) {
#pragma unroll
        for (int ks = 0; ks < 2; ++ks) {
#pragma unroll
            for (int j = 0; j < 8; ++j) {
                int kk = ks * 32 + quad * 8 + j;
                float w = (kk < HID) ? Wo2[kk * 32 + nt * 16 + l16] : 0.f;
                bfrag[nt][ks][j] = (short)f2bf(w);
            }
        }
    }
    short8 zfrag = {0, 0, 0, 0, 0, 0, 0, 0};
    __syncthreads();

    // prefetch tile 0
    int t = blockIdx.x;
    int pb = -1;
    uint4 pxe = {0u, 0u, 0u, 0u};
    {
        int i = t * TILE + tid;
        bool v = i < N_POINTS;
        int ic = v ? i : (N_POINTS - 1);
        pb = v ? batch[ic] : -1;
        if (use_xe) pxe = *(const uint4*)&xe_in[(size_t)ic * 8];
    }

    for (; t < NTILES; t += GRID_C) {
        int i = t * TILE + tid;
        bool v = i < N_POINTS;
        int ic = v ? i : (N_POINTS - 1);
        int b = pb;
        uint4 xe4 = pxe;
        sb[tid] = b;

        // prefetch next tile (registers only; sb untouched)
        int tn = t + GRID_C;
        if (tn < NTILES) {
            int i2 = tn * TILE + tid;
            bool v2 = i2 < N_POINTS;
            int ic2 = v2 ? i2 : (N_POINTS - 1);
            pb = v2 ? batch[ic2] : -1;
            if (use_xe) pxe = *(const uint4*)&xe_in[(size_t)ic2 * 8];
        }

        float xe[5];
        if (use_xe) {
            xe[0] = bflo(xe4.x); xe[1] = bfhi(xe4.x);
            xe[2] = bflo(xe4.y); xe[3] = bfhi(xe4.y);
            xe[4] = bflo(xe4.z);
        } else {
            float x0 = x[ic * 3 + 0], x1 = x[ic * 3 + 1], x2 = x[ic * 3 + 2];
            float h[HID];
            const float4* W1r = (const float4*)sWe1;
#pragma unroll
            for (int j4 = 0; j4 < HID / 4; ++j4) {
                float4 wa = W1r[j4], wb = W1r[10 + j4], wc = W1r[20 + j4];
                float wav[4] = {wa.x, wa.y, wa.z, wa.w};
                float wbv[4] = {wb.x, wb.y, wb.z, wb.w};
                float wcv[4] = {wc.x, wc.y, wc.z, wc.w};
#pragma unroll
                for (int k = 0; k < 4; ++k)
                    h[j4 * 4 + k] = lrelu(x0 * wav[k] + x1 * wbv[k] + x2 * wcv[k]);
            }
#pragma unroll
            for (int c = 0; c < 5; ++c) {
                const float4* wr = (const float4*)&sWe2T[c * HID];
                float s = 0.f;
#pragma unroll
                for (int j4 = 0; j4 < HID / 4; ++j4) {
                    float4 w = wr[j4];
                    s += h[j4 * 4 + 0] * w.x + h[j4 * 4 + 1] * w.y + h[j4 * 4 + 2] * w.z + h[j4 * 4 + 3] * w.w;
                }
                xe[c] = lrelu(s);
            }
        }

        // h1 = lrelu(xe @ Wo1[0:5] + g_contrib[b]); pack bf16; stage A row (wave-private rows)
        const float4* gc4 = (const float4*)(g_contrib + (size_t)(v ? b : 0) * HID);
        unsigned int* row = &uLds[tid * AROW];
#pragma unroll
        for (int j4 = 0; j4 < HID / 4; ++j4) {
            float4 g = gc4[j4];
            float sv[4] = {g.x, g.y, g.z, g.w};
#pragma unroll
            for (int c = 0; c < 5; ++c) {
                float4 w = ((const float4*)&sWo1[c * HID])[j4];
                float wvv[4] = {w.x, w.y, w.z, w.w};
#pragma unroll
                for (int k = 0; k < 4; ++k) sv[k] += xe[c] * wvv[k];
            }
            uint2 u;
            u.x = packbf2(lrelu(sv[0]), lrelu(sv[1]));
            u.y = packbf2(lrelu(sv[2]), lrelu(sv[3]));
            *(uint2*)(row + j4 * 2) = u;
        }

        // MFMA: wave owns mtiles 4w..4w+3; 2 ntiles; K = 32 + 8 (second frag zero for quad>0)
        fx4 xov[4][2];
#pragma unroll
        for (int m = 0; m < 4; ++m) {
            int mt = (tid >> 6) * 4 + m;
            const unsigned int* arow = &uLds[(mt * 16 + l16) * AROW];
            short8 a0 = *(const short8*)(arow + quad * 4);
            short8 a1 = (quad == 0) ? *(const short8*)(arow + 16) : zfrag;
#pragma unroll
            for (int nt = 0; nt < 2; ++nt) {
                fx4 acc = {0.f, 0.f, 0.f, 0.f};
                acc = __builtin_amdgcn_mfma_f32_16x16x32_bf16(a0, bfrag[nt][0], acc, 0, 0, 0);
                acc = __builtin_amdgcn_mfma_f32_16x16x32_bf16(a1, bfrag[nt][1], acc, 0, 0, 0);
#pragma unroll
                for (int r = 0; r < 4; ++r) acc[r] = lrelu(acc[r]);
                xov[m][nt] = acc;
            }
        }
        __syncthreads();   // all A-frag reads done -> safe to clobber staging with xoT

        // two 16-channel pool halves through the aliased region
        float* xoT = (float*)uLds;
#pragma unroll 1
        for (int half = 0; half < 2; ++half) {
            // C layout: col = l16 = channel-within-half, row = quad*4 + r = point
#pragma unroll
            for (int m = 0; m < 4; ++m) {
                int mt = (tid >> 6) * 4 + m;
                int pt = mt * 16 + quad * 4;
                *(fx4*)&xoT[l16 * XOS + pt] = xov[m][half];
            }
            __syncthreads();

            // chunk-reduce: tid<128: ch = tid&15, chunk = tid>>4 (8 chunks of 32 pts)
            if (tid < 128) {
                int ch = tid & 15, chunk = tid >> 4;
                float acc = 0.f;
                int cur = sb[chunk * 32];
#pragma unroll
                for (int g = 0; g < 8; ++g) {
                    float4 v4 = *(const float4*)&xoT[ch * XOS + chunk * 32 + g * 4];
                    int4   n4 = *(const int4*)&sb[chunk * 32 + g * 4];
                    float vv[4] = {v4.x, v4.y, v4.z, v4.w};
                    int   nn[4] = {n4.x, n4.y, n4.z, n4.w};
#pragma unroll
                    for (int k = 0; k < 4; ++k) {
                        if (nn[k] != cur) {
                            if (cur >= 0) atomicAdd(&pooled[cur * 32 + half * 16 + ch], acc);
                            cur = nn[k];
                            acc = vv[k];
                        } else {
                            acc += vv[k];
                        }
                    }
                }
                if (cur >= 0) atomicAdd(&pooled[cur * 32 + half * 16 + ch], acc);
            }
            __syncthreads();
        }
    }
}

// ---------------- Pass D: disc head per graph ----------------
__global__ __launch_bounds__(256) void k_disc(
    const float* __restrict__ pooled,
    const float* __restrict__ Wd1, const float* __restrict__ Wd2,
    float* __restrict__ out)
{
    __shared__ float sWd1T[HID * 32];  // [j][c]
    __shared__ float sWd2[HID];
    for (int k = threadIdx.x; k < 32 * HID; k += 256) sWd1T[k] = Wd1[(k % 32) * HID + k / 32];
    for (int k = threadIdx.x; k < HID; k += 256) sWd2[k] = Wd2[k];
    __syncthreads();

    int bg = blockIdx.x * 256 + threadIdx.x;
    if (bg >= NUM_GRAPHS) return;

    float p[32];
    const float4* pp = (const float4*)(pooled + (size_t)bg * 32);
#pragma unroll
    for (int c4 = 0; c4 < 8; ++c4) {
        float4 vv = pp[c4];
        p[c4 * 4 + 0] = vv.x; p[c4 * 4 + 1] = vv.y; p[c4 * 4 + 2] = vv.z; p[c4 * 4 + 3] = vv.w;
    }

    float acc = 0.f;
#pragma unroll
    for (int j = 0; j < HID; ++j) {
        const float4* wr = (const float4*)&sWd1T[j * 32];
        float s = 0.f;
#pragma unroll
        for (int c4 = 0; c4 < 8; ++c4) {
            float4 w = wr[c4];
            s += p[c4 * 4 + 0] * w.x + p[c4 * 4 + 1] * w.y + p[c4 * 4 + 2] * w.z + p[c4 * 4 + 3] * w.w;
        }
        acc += lrelu(s) * sWd2[j];
    }
    out[bg] = acc;
}

extern "C" void kernel_launch(void* const* d_in, const int* in_sizes, int n_in,
                              void* d_out, int out_size, void* d_ws, size_t ws_size,
                              hipStream_t stream) {
    const float* x     = (const float*)d_in[0];
    const int*   batch = (const int*)  d_in[1];
    const float* We1   = (const float*)d_in[2];
    const float* We2   = (const float*)d_in[3];
    const float* Wg1   = (const float*)d_in[4];
    const float* Wg2   = (const float*)d_in[5];
    const float* Wo1   = (const float*)d_in[6];
    const float* Wo2   = (const float*)d_in[7];
    const float* Wd1   = (const float*)d_in[8];
    const float* Wd2   = (const float*)d_in[9];
    float* out = (float*)d_out;

    // ws layout: [x_aggr B*5][pooled B*32][g_contrib B*40][xe bf16 interleaved N*8]
    float* x_aggr    = (float*)d_ws;
    float* pooled    = x_aggr + NUM_GRAPHS * 5;
    float* g_contrib = pooled + NUM_GRAPHS * 32;
    size_t head_bytes = (size_t)NUM_GRAPHS * (5 + 32 + HID) * sizeof(float);  // 16B-aligned
    unsigned short* xe_ws = (unsigned short*)((char*)d_ws + head_bytes);
    size_t need = head_bytes + (size_t)N_POINTS * 8 * sizeof(unsigned short);
    int use_xe = (ws_size >= need) ? 1 : 0;

    hipMemsetAsync(d_ws, 0, (size_t)NUM_GRAPHS * (5 + 32) * sizeof(float), stream);

    int gblk = (NUM_GRAPHS + 255) / 256;
    k_emb_aggr<<<NT_A, 256, 0, stream>>>(x, batch, We1, We2, x_aggr, xe_ws, use_xe);
    k_global <<<gblk, 256, 0, stream>>>(x_aggr, Wg1, Wg2, Wo1, g_contrib);
    k_out_pool<<<GRID_C, 256, 0, stream>>>(x, batch, We1, We2, Wo1, Wo2, g_contrib,
                                           xe_ws, use_xe, pooled);
    k_disc   <<<gblk, 256, 0, stream>>>(pooled, Wd1, Wd2, out);
}

// Round 9
// 284.794 us; speedup vs baseline: 1.1704x; 1.1704x over previous
//
#include <hip/hip_runtime.h>
#include <hip/hip_bf16.h>

#define N_POINTS   2000000
#define NUM_GRAPHS 16384
#define HID        40
#define SLOPE      0.01f

// Pass A tiling: 512 pts/block, 2 pts/thread
#define TILE_A     512
#define NT_A       ((N_POINTS + TILE_A - 1) / TILE_A)   // 3907
#define XESA       584    // dwords per xeT channel row (chunk-padded max idx 571; %32==8; 16B aligned)

// Pass C tiling: 256 pts/tile, grid-stride
#define TILE       256
#define NTILES     ((N_POINTS + TILE - 1) / TILE)       // 7813
#define AROW       20     // dwords per bf16 A-staging row (40 bf16)
#define XOS        260    // dwords per xoT channel row (%32==4, 16B aligned)
#define GRID_C     1536   // up to 6 blocks/CU (LDS-limited); grid-stride tolerates fewer

typedef __attribute__((ext_vector_type(8))) short short8;
typedef __attribute__((ext_vector_type(4))) float fx4;

__device__ __forceinline__ float lrelu(float v) { return v > 0.f ? v : SLOPE * v; }
__device__ __forceinline__ int padidx(int p) { return p + ((p >> 5) << 2); }  // +4 dwords per 32-chunk
__device__ __forceinline__ unsigned short f2bf(float f) {
    __hip_bfloat16 h = __float2bfloat16(f);
    return *(unsigned short*)&h;
}
__device__ __forceinline__ unsigned int packbf2(float a, float b) {
    __hip_bfloat162 p = __float22bfloat162_rn(make_float2(a, b));
    return *(unsigned int*)&p;
}
__device__ __forceinline__ float bflo(unsigned int d) { return __uint_as_float(d << 16); }
__device__ __forceinline__ float bfhi(unsigned int d) { return __uint_as_float(d & 0xffff0000u); }

// ---------------- Pass A: emb FFN (2 pts/thread) + transpose-reduce + xe bf16 cache ----------------
__global__ __launch_bounds__(256) void k_emb_aggr(
    const float* __restrict__ x, const int* __restrict__ batch,
    const float* __restrict__ We1, const float* __restrict__ We2,
    float* __restrict__ x_aggr, unsigned short* __restrict__ xe_out, int use_xe)
{
    __shared__ __align__(16) float sWe1[3 * HID];
    __shared__ __align__(16) float sWe2T[5 * HID];          // [c][j]
    __shared__ __align__(16) float xeT[5 * XESA];           // chunk-padded
    __shared__ __align__(16) int   sbp[XESA];

    int tid = threadIdx.x;
    for (int k = tid; k < 3 * HID; k += 256) sWe1[k] = We1[k];
    for (int k = tid; k < 5 * HID; k += 256) sWe2T[k] = We2[(k % HID) * 5 + k / HID];
    __syncthreads();

    int base = blockIdx.x * TILE_A;
    int p0 = base + tid, p1 = base + 256 + tid;
    bool v0 = p0 < N_POINTS, v1 = p1 < N_POINTS;
    int i0 = v0 ? p0 : (N_POINTS - 1), i1 = v1 ? p1 : (N_POINTS - 1);
    float a0 = x[i0 * 3 + 0], a1 = x[i0 * 3 + 1], a2 = x[i0 * 3 + 2];
    float c0 = x[i1 * 3 + 0], c1 = x[i1 * 3 + 1], c2 = x[i1 * 3 + 2];
    int b0 = v0 ? batch[i0] : -1;
    int b1 = v1 ? batch[i1] : -1;
    sbp[padidx(tid)] = b0;
    sbp[padidx(256 + tid)] = b1;

    // layer 1: one weight read feeds 2 points
    float h0[HID], h1[HID];
    const float4* W1r = (const float4*)sWe1;
#pragma unroll
    for (int j4 = 0; j4 < HID / 4; ++j4) {
        float4 wa = W1r[j4], wb = W1r[10 + j4], wc = W1r[20 + j4];
        float wav[4] = {wa.x, wa.y, wa.z, wa.w};
        float wbv[4] = {wb.x, wb.y, wb.z, wb.w};
        float wcv[4] = {wc.x, wc.y, wc.z, wc.w};
#pragma unroll
        for (int k = 0; k < 4; ++k) {
            int j = j4 * 4 + k;
            h0[j] = lrelu(a0 * wav[k] + a1 * wbv[k] + a2 * wcv[k]);
            h1[j] = lrelu(c0 * wav[k] + c1 * wbv[k] + c2 * wcv[k]);
        }
    }

    // layer 2 + stage (fp32 into aggregation; bf16 into cache)
    float e0v[5], e1v[5];
#pragma unroll
    for (int c = 0; c < 5; ++c) {
        const float4* wr = (const float4*)&sWe2T[c * HID];
        float s0 = 0.f, s1 = 0.f;
#pragma unroll
        for (int j4 = 0; j4 < HID / 4; ++j4) {
            float4 w = wr[j4];
            float wv[4] = {w.x, w.y, w.z, w.w};
#pragma unroll
            for (int k = 0; k < 4; ++k) {
                s0 += h0[j4 * 4 + k] * wv[k];
                s1 += h1[j4 * 4 + k] * wv[k];
            }
        }
        e0v[c] = v0 ? lrelu(s0) : 0.f;
        e1v[c] = v1 ? lrelu(s1) : 0.f;
        xeT[c * XESA + padidx(tid)] = e0v[c];
        xeT[c * XESA + padidx(256 + tid)] = e1v[c];
    }
    if (use_xe) {
        if (v0) {
            uint4 u;
            u.x = packbf2(e0v[0], e0v[1]); u.y = packbf2(e0v[2], e0v[3]);
            u.z = packbf2(e0v[4], 0.f);    u.w = 0u;
            *(uint4*)&xe_out[(size_t)p0 * 8] = u;
        }
        if (v1) {
            uint4 u;
            u.x = packbf2(e1v[0], e1v[1]); u.y = packbf2(e1v[2], e1v[3]);
            u.z = packbf2(e1v[4], 0.f);    u.w = 0u;
            *(uint4*)&xe_out[(size_t)p1 * 8] = u;
        }
    }
    __syncthreads();

    // reduce: thread tid<80 owns (ch = tid>>4 in 0..4, chunk = tid&15 of 32 pts)
    if (tid < 80) {
        int ch = tid >> 4, chunk = tid & 15;
        float acc = 0.f;
        int cur = sbp[chunk * 36];
#pragma unroll
        for (int g = 0; g < 8; ++g) {
            float4 v4 = *(const float4*)&xeT[ch * XESA + chunk * 36 + g * 4];
            int4   n4 = *(const int4*)&sbp[chunk * 36 + g * 4];
            float vv[4] = {v4.x, v4.y, v4.z, v4.w};
            int   nn[4] = {n4.x, n4.y, n4.z, n4.w};
#pragma unroll
            for (int k = 0; k < 4; ++k) {
                if (nn[k] != cur) {
                    if (cur >= 0) atomicAdd(&x_aggr[cur * 5 + ch], acc);
                    cur = nn[k];
                    acc = vv[k];
                } else {
                    acc += vv[k];
                }
            }
        }
        if (cur >= 0) atomicAdd(&x_aggr[cur * 5 + ch], acc);
    }
}

// ---------------- Pass B: per-graph global FFN + fold into W_out1 rows 5..8 ----------------
__global__ __launch_bounds__(256) void k_global(
    const float* __restrict__ x_aggr,
    const float* __restrict__ Wg1, const float* __restrict__ Wg2,
    const float* __restrict__ Wo1,
    float* __restrict__ g_contrib)
{
    __shared__ float sWg1[5 * HID];
    __shared__ float sWg2[HID * 4];
    __shared__ float sWo1g[4 * HID];
    for (int k = threadIdx.x; k < 5 * HID; k += 256) sWg1[k] = Wg1[k];
    for (int k = threadIdx.x; k < HID * 4; k += 256) sWg2[k] = Wg2[k];
    for (int k = threadIdx.x; k < 4 * HID; k += 256) sWo1g[k] = Wo1[5 * HID + k];
    __syncthreads();

    int bg = blockIdx.x * 256 + threadIdx.x;
    if (bg >= NUM_GRAPHS) return;

    float a[5];
#pragma unroll
    for (int c = 0; c < 5; ++c) a[c] = x_aggr[bg * 5 + c];

    float h[HID];
#pragma unroll
    for (int j = 0; j < HID; ++j) {
        float s = 0.f;
#pragma unroll
        for (int c = 0; c < 5; ++c) s += a[c] * sWg1[c * HID + j];
        h[j] = lrelu(s);
    }
    float g[4];
#pragma unroll
    for (int c = 0; c < 4; ++c) {
        float s = 0.f;
#pragma unroll
        for (int j = 0; j < HID; ++j) s += h[j] * sWg2[j * 4 + c];
        g[c] = lrelu(s);
    }
#pragma unroll
    for (int j = 0; j < HID; ++j) {
        float s = 0.f;
#pragma unroll
        for (int c = 0; c < 4; ++c) s += g[c] * sWo1g[c * HID + j];
        g_contrib[bg * HID + j] = s;
    }
}

// ---------------- Pass C: prefetched xe load, h1 VALU, 40x32 bf16 MFMA, two-half transpose-pool ----------------
// Two-half pool loop is FULLY UNROLLED: xov[m][half] must be compile-time-indexed.
// R7/R8 lesson: `#pragma unroll 1` + xov[m][half] (runtime idx) demotes xov to scratch
// -> 250+ MB WRITE_SIZE, 2x regression, regardless of launch_bounds.
__global__ __launch_bounds__(256, 4) void k_out_pool(
    const float* __restrict__ x, const int* __restrict__ batch,
    const float* __restrict__ We1, const float* __restrict__ We2,
    const float* __restrict__ Wo1, const float* __restrict__ Wo2,
    const float* __restrict__ g_contrib,
    const unsigned short* __restrict__ xe_in, int use_xe,
    float* __restrict__ pooled)
{
    // Aliased region: A-staging (256 rows x 20 dw = 20480 B) / xoT half (16 x 260 x 4 = 16640 B)
    __shared__ __align__(16) unsigned int uLds[TILE * AROW];
    __shared__ __align__(16) int sb[TILE];
    __shared__ float sWe1[3 * HID];      // fallback path only
    __shared__ float sWe2T[5 * HID];     // fallback path only
    __shared__ float sWo1[5 * HID];

    int tid = threadIdx.x;
    for (int k = tid; k < 3 * HID; k += 256) sWe1[k] = We1[k];
    for (int k = tid; k < 5 * HID; k += 256) sWe2T[k] = We2[(k % HID) * 5 + k / HID];
    for (int k = tid; k < 5 * HID; k += 256) sWo1[k] = Wo1[k];

    int lane = tid & 63;
    int l16 = lane & 15, quad = lane >> 4;

    // B fragments (Wo2 -> bf16), built once: lane l16 = n, k = ks*32 + quad*8 + j
    short8 bfrag[2][2];
#pragma unroll
    for (int nt = 0; nt < 2; ++nt) {
#pragma unroll
        for (int ks = 0; ks < 2; ++ks) {
#pragma unroll
            for (int j = 0; j < 8; ++j) {
                int kk = ks * 32 + quad * 8 + j;
                float w = (kk < HID) ? Wo2[kk * 32 + nt * 16 + l16] : 0.f;
                bfrag[nt][ks][j] = (short)f2bf(w);
            }
        }
    }
    short8 zfrag = {0, 0, 0, 0, 0, 0, 0, 0};
    __syncthreads();

    // prefetch tile 0
    int t = blockIdx.x;
    int pb = -1;
    uint4 pxe = {0u, 0u, 0u, 0u};
    {
        int i = t * TILE + tid;
        bool v = i < N_POINTS;
        int ic = v ? i : (N_POINTS - 1);
        pb = v ? batch[ic] : -1;
        if (use_xe) pxe = *(const uint4*)&xe_in[(size_t)ic * 8];
    }

    for (; t < NTILES; t += GRID_C) {
        int i = t * TILE + tid;
        bool v = i < N_POINTS;
        int ic = v ? i : (N_POINTS - 1);
        int b = pb;
        uint4 xe4 = pxe;
        sb[tid] = b;

        // prefetch next tile (registers only; sb untouched)
        int tn = t + GRID_C;
        if (tn < NTILES) {
            int i2 = tn * TILE + tid;
            bool v2 = i2 < N_POINTS;
            int ic2 = v2 ? i2 : (N_POINTS - 1);
            pb = v2 ? batch[ic2] : -1;
            if (use_xe) pxe = *(const uint4*)&xe_in[(size_t)ic2 * 8];
        }

        float xe[5];
        if (use_xe) {
            xe[0] = bflo(xe4.x); xe[1] = bfhi(xe4.x);
            xe[2] = bflo(xe4.y); xe[3] = bfhi(xe4.y);
            xe[4] = bflo(xe4.z);
        } else {
            float x0 = x[ic * 3 + 0], x1 = x[ic * 3 + 1], x2 = x[ic * 3 + 2];
            float h[HID];
            const float4* W1r = (const float4*)sWe1;
#pragma unroll
            for (int j4 = 0; j4 < HID / 4; ++j4) {
                float4 wa = W1r[j4], wb = W1r[10 + j4], wc = W1r[20 + j4];
                float wav[4] = {wa.x, wa.y, wa.z, wa.w};
                float wbv[4] = {wb.x, wb.y, wb.z, wb.w};
                float wcv[4] = {wc.x, wc.y, wc.z, wc.w};
#pragma unroll
                for (int k = 0; k < 4; ++k)
                    h[j4 * 4 + k] = lrelu(x0 * wav[k] + x1 * wbv[k] + x2 * wcv[k]);
            }
#pragma unroll
            for (int c = 0; c < 5; ++c) {
                const float4* wr = (const float4*)&sWe2T[c * HID];
                float s = 0.f;
#pragma unroll
                for (int j4 = 0; j4 < HID / 4; ++j4) {
                    float4 w = wr[j4];
                    s += h[j4 * 4 + 0] * w.x + h[j4 * 4 + 1] * w.y + h[j4 * 4 + 2] * w.z + h[j4 * 4 + 3] * w.w;
                }
                xe[c] = lrelu(s);
            }
        }

        // h1 = lrelu(xe @ Wo1[0:5] + g_contrib[b]); pack bf16; stage A row (wave-private rows)
        const float4* gc4 = (const float4*)(g_contrib + (size_t)(v ? b : 0) * HID);
        unsigned int* row = &uLds[tid * AROW];
#pragma unroll
        for (int j4 = 0; j4 < HID / 4; ++j4) {
            float4 g = gc4[j4];
            float sv[4] = {g.x, g.y, g.z, g.w};
#pragma unroll
            for (int c = 0; c < 5; ++c) {
                float4 w = ((const float4*)&sWo1[c * HID])[j4];
                float wvv[4] = {w.x, w.y, w.z, w.w};
#pragma unroll
                for (int k = 0; k < 4; ++k) sv[k] += xe[c] * wvv[k];
            }
            uint2 u;
            u.x = packbf2(lrelu(sv[0]), lrelu(sv[1]));
            u.y = packbf2(lrelu(sv[2]), lrelu(sv[3]));
            *(uint2*)(row + j4 * 2) = u;
        }

        // MFMA: wave owns mtiles 4w..4w+3; 2 ntiles; K = 32 + 8 (second frag zero for quad>0)
        fx4 xov[4][2];
#pragma unroll
        for (int m = 0; m < 4; ++m) {
            int mt = (tid >> 6) * 4 + m;
            const unsigned int* arow = &uLds[(mt * 16 + l16) * AROW];
            short8 a0 = *(const short8*)(arow + quad * 4);
            short8 a1 = (quad == 0) ? *(const short8*)(arow + 16) : zfrag;
#pragma unroll
            for (int nt = 0; nt < 2; ++nt) {
                fx4 acc = {0.f, 0.f, 0.f, 0.f};
                acc = __builtin_amdgcn_mfma_f32_16x16x32_bf16(a0, bfrag[nt][0], acc, 0, 0, 0);
                acc = __builtin_amdgcn_mfma_f32_16x16x32_bf16(a1, bfrag[nt][1], acc, 0, 0, 0);
#pragma unroll
                for (int r = 0; r < 4; ++r) acc[r] = lrelu(acc[r]);
                xov[m][nt] = acc;
            }
        }
        __syncthreads();   // all A-frag reads done -> safe to clobber staging with xoT

        // two 16-channel pool halves through the aliased region (FULLY unrolled: half const)
        float* xoT = (float*)uLds;
#pragma unroll
        for (int half = 0; half < 2; ++half) {
            // C layout: col = l16 = channel-within-half, row = quad*4 + r = point
#pragma unroll
            for (int m = 0; m < 4; ++m) {
                int mt = (tid >> 6) * 4 + m;
                int pt = mt * 16 + quad * 4;
                *(fx4*)&xoT[l16 * XOS + pt] = xov[m][half];
            }
            __syncthreads();

            // chunk-reduce: tid<128: ch = tid&15, chunk = tid>>4 (8 chunks of 32 pts)
            if (tid < 128) {
                int ch = tid & 15, chunk = tid >> 4;
                float acc = 0.f;
                int cur = sb[chunk * 32];
#pragma unroll
                for (int g = 0; g < 8; ++g) {
                    float4 v4 = *(const float4*)&xoT[ch * XOS + chunk * 32 + g * 4];
                    int4   n4 = *(const int4*)&sb[chunk * 32 + g * 4];
                    float vv[4] = {v4.x, v4.y, v4.z, v4.w};
                    int   nn[4] = {n4.x, n4.y, n4.z, n4.w};
#pragma unroll
                    for (int k = 0; k < 4; ++k) {
                        if (nn[k] != cur) {
                            if (cur >= 0) atomicAdd(&pooled[cur * 32 + half * 16 + ch], acc);
                            cur = nn[k];
                            acc = vv[k];
                        } else {
                            acc += vv[k];
                        }
                    }
                }
                if (cur >= 0) atomicAdd(&pooled[cur * 32 + half * 16 + ch], acc);
            }
            __syncthreads();
        }
    }
}

// ---------------- Pass D: disc head per graph ----------------
__global__ __launch_bounds__(256) void k_disc(
    const float* __restrict__ pooled,
    const float* __restrict__ Wd1, const float* __restrict__ Wd2,
    float* __restrict__ out)
{
    __shared__ float sWd1T[HID * 32];  // [j][c]
    __shared__ float sWd2[HID];
    for (int k = threadIdx.x; k < 32 * HID; k += 256) sWd1T[k] = Wd1[(k % 32) * HID + k / 32];
    for (int k = threadIdx.x; k < HID; k += 256) sWd2[k] = Wd2[k];
    __syncthreads();

    int bg = blockIdx.x * 256 + threadIdx.x;
    if (bg >= NUM_GRAPHS) return;

    float p[32];
    const float4* pp = (const float4*)(pooled + (size_t)bg * 32);
#pragma unroll
    for (int c4 = 0; c4 < 8; ++c4) {
        float4 vv = pp[c4];
        p[c4 * 4 + 0] = vv.x; p[c4 * 4 + 1] = vv.y; p[c4 * 4 + 2] = vv.z; p[c4 * 4 + 3] = vv.w;
    }

    float acc = 0.f;
#pragma unroll
    for (int j = 0; j < HID; ++j) {
        const float4* wr = (const float4*)&sWd1T[j * 32];
        float s = 0.f;
#pragma unroll
        for (int c4 = 0; c4 < 8; ++c4) {
            float4 w = wr[c4];
            s += p[c4 * 4 + 0] * w.x + p[c4 * 4 + 1] * w.y + p[c4 * 4 + 2] * w.z + p[c4 * 4 + 3] * w.w;
        }
        acc += lrelu(s) * sWd2[j];
    }
    out[bg] = acc;
}

extern "C" void kernel_launch(void* const* d_in, const int* in_sizes, int n_in,
                              void* d_out, int out_size, void* d_ws, size_t ws_size,
                              hipStream_t stream) {
    const float* x     = (const float*)d_in[0];
    const int*   batch = (const int*)  d_in[1];
    const float* We1   = (const float*)d_in[2];
    const float* We2   = (const float*)d_in[3];
    const float* Wg1   = (const float*)d_in[4];
    const float* Wg2   = (const float*)d_in[5];
    const float* Wo1   = (const float*)d_in[6];
    const float* Wo2   = (const float*)d_in[7];
    const float* Wd1   = (const float*)d_in[8];
    const float* Wd2   = (const float*)d_in[9];
    float* out = (float*)d_out;

    // ws layout: [x_aggr B*5][pooled B*32][g_contrib B*40][xe bf16 interleaved N*8]
    float* x_aggr    = (float*)d_ws;
    float* pooled    = x_aggr + NUM_GRAPHS * 5;
    float* g_contrib = pooled + NUM_GRAPHS * 32;
    size_t head_bytes = (size_t)NUM_GRAPHS * (5 + 32 + HID) * sizeof(float);  // 16B-aligned
    unsigned short* xe_ws = (unsigned short*)((char*)d_ws + head_bytes);
    size_t need = head_bytes + (size_t)N_POINTS * 8 * sizeof(unsigned short);
    int use_xe = (ws_size >= need) ? 1 : 0;

    hipMemsetAsync(d_ws, 0, (size_t)NUM_GRAPHS * (5 + 32) * sizeof(float), stream);

    int gblk = (NUM_GRAPHS + 255) / 256;
    k_emb_aggr<<<NT_A, 256, 0, stream>>>(x, batch, We1, We2, x_aggr, xe_ws, use_xe);
    k_global <<<gblk, 256, 0, stream>>>(x_aggr, Wg1, Wg2, Wo1, g_contrib);
    k_out_pool<<<GRID_C, 256, 0, stream>>>(x, batch, We1, We2, Wo1, Wo2, g_contrib,
                                           xe_ws, use_xe, pooled);
    k_disc   <<<gblk, 256, 0, stream>>>(pooled, Wd1, Wd2, out);
}

// Round 10
// 275.516 us; speedup vs baseline: 1.2098x; 1.0337x over previous
//
#include <hip/hip_runtime.h>
#include <hip/hip_bf16.h>

#define N_POINTS   2000000
#define NUM_GRAPHS 16384
#define HID        40
#define SLOPE      0.01f

// Pass A (emb): 256 pts/block, 1 pt/thread, MFMA layer2
#define TILE_E     256
#define NT_E       ((N_POINTS + TILE_E - 1) / TILE_E)   // 7813

// Pass C tiling: 256 pts/tile, grid-stride
#define TILE       256
#define NTILES     ((N_POINTS + TILE - 1) / TILE)       // 7813
#define AROW       20     // dwords per bf16 A-staging row (40 bf16)
#define XOS        260    // dwords per xoT/xeT channel row (%32==4, 16B aligned)
#define GRID_C     1536

typedef __attribute__((ext_vector_type(8))) short short8;
typedef __attribute__((ext_vector_type(4))) float fx4;

__device__ __forceinline__ float lrelu(float v) { return v > 0.f ? v : SLOPE * v; }
__device__ __forceinline__ unsigned short f2bf(float f) {
    __hip_bfloat16 h = __float2bfloat16(f);
    return *(unsigned short*)&h;
}
__device__ __forceinline__ unsigned int packbf2(float a, float b) {
    __hip_bfloat162 p = __float22bfloat162_rn(make_float2(a, b));
    return *(unsigned int*)&p;
}
__device__ __forceinline__ float bflo(unsigned int d) { return __uint_as_float(d << 16); }
__device__ __forceinline__ float bfhi(unsigned int d) { return __uint_as_float(d & 0xffff0000u); }

// ---------------- Pass A: emb layer1 VALU (packed bf16), layer2 MFMA, xeT reduce + cache ----------------
// R9 lesson: h0/h1[40] fp32 + e-arrays -> VGPR 136 -> 3 waves/SIMD, 107 us. This version packs h
// to bf16 on the fly (20 u32) and gets xe via MFMA C-layout through LDS: VGPR ~64 target.
__global__ __launch_bounds__(256) void k_emb_aggr(
    const float* __restrict__ x, const int* __restrict__ batch,
    const float* __restrict__ We1, const float* __restrict__ We2,
    float* __restrict__ x_aggr, unsigned short* __restrict__ xe_out, int use_xe)
{
    // A-staging (256 x 20 dw = 20480 B) aliased (after barrier) with xeT (5 x 260 dw = 5200 B)
    __shared__ __align__(16) unsigned int uLds[TILE_E * AROW];
    __shared__ __align__(16) int sb[TILE_E];
    __shared__ __align__(16) float sWe1[3 * HID];

    int tid = threadIdx.x;
    for (int k = tid; k < 3 * HID; k += 256) sWe1[k] = We1[k];

    int lane = tid & 63;
    int l16 = lane & 15, quad = lane >> 4;

    // B fragments for layer2: B[k][n] = We2[k*5+n]; lane n=l16 (valid n<5), k=ks*32+quad*8+j
    short8 bfrag[2];
#pragma unroll
    for (int ks = 0; ks < 2; ++ks) {
#pragma unroll
        for (int j = 0; j < 8; ++j) {
            int kk = ks * 32 + quad * 8 + j;
            float w = (kk < HID && l16 < 5) ? We2[kk * 5 + l16] : 0.f;
            bfrag[ks][j] = (short)f2bf(w);
        }
    }
    short8 zfrag = {0, 0, 0, 0, 0, 0, 0, 0};
    __syncthreads();

    int i = blockIdx.x * TILE_E + tid;
    bool v = i < N_POINTS;
    int ic = v ? i : (N_POINTS - 1);
    float x0 = x[ic * 3 + 0], x1 = x[ic * 3 + 1], x2 = x[ic * 3 + 2];
    int b = v ? batch[ic] : -1;
    sb[tid] = b;

    // layer1: h = lrelu(x @ We1), packed to bf16 pairs as computed (20 u32 of state)
    unsigned int hpk[2 * (HID / 4)];
    const float4* W1r = (const float4*)sWe1;
#pragma unroll
    for (int j4 = 0; j4 < HID / 4; ++j4) {
        float4 wa = W1r[j4], wb = W1r[10 + j4], wc = W1r[20 + j4];
        float hv0 = lrelu(x0 * wa.x + x1 * wb.x + x2 * wc.x);
        float hv1 = lrelu(x0 * wa.y + x1 * wb.y + x2 * wc.y);
        float hv2 = lrelu(x0 * wa.z + x1 * wb.z + x2 * wc.z);
        float hv3 = lrelu(x0 * wa.w + x1 * wb.w + x2 * wc.w);
        hpk[j4 * 2 + 0] = packbf2(hv0, hv1);
        hpk[j4 * 2 + 1] = packbf2(hv2, hv3);
    }

    // stage A row (wave-private rows: wave w stages tids 64w..64w+63, reads mtiles 4w..4w+3)
    unsigned int* row = &uLds[tid * AROW];
#pragma unroll
    for (int j4 = 0; j4 < HID / 4; ++j4) {
        uint2 u;
        u.x = hpk[j4 * 2 + 0];
        u.y = hpk[j4 * 2 + 1];
        *(uint2*)(row + j4 * 2) = u;
    }

    // MFMA layer2: wave owns mtiles 4w..4w+3; 1 ntile (5 of 16 cols used); K=32+8
    fx4 acc[4];
#pragma unroll
    for (int m = 0; m < 4; ++m) {
        int mt = (tid >> 6) * 4 + m;
        const unsigned int* arow = &uLds[(mt * 16 + l16) * AROW];
        short8 a0 = *(const short8*)(arow + quad * 4);
        short8 a1 = (quad == 0) ? *(const short8*)(arow + 16) : zfrag;
        fx4 c = {0.f, 0.f, 0.f, 0.f};
        c = __builtin_amdgcn_mfma_f32_16x16x32_bf16(a0, bfrag[0], c, 0, 0, 0);
        c = __builtin_amdgcn_mfma_f32_16x16x32_bf16(a1, bfrag[1], c, 0, 0, 0);
#pragma unroll
        for (int r = 0; r < 4; ++r) c[r] = lrelu(c[r]);
        acc[m] = c;
    }
    __syncthreads();   // all A-reads done -> safe to clobber staging with xeT

    // C layout: col=l16=channel (<5 valid), row=quad*4+r=pt -> fx4 of 4 consecutive pts
    float* xeT = (float*)uLds;
    if (l16 < 5) {
#pragma unroll
        for (int m = 0; m < 4; ++m) {
            int mt = (tid >> 6) * 4 + m;
            *(fx4*)&xeT[l16 * XOS + mt * 16 + quad * 4] = acc[m];
        }
    }
    __syncthreads();

    // interleaved bf16 xe cache: one uint4 store per point
    if (use_xe && v) {
        float e0 = xeT[0 * XOS + tid], e1 = xeT[1 * XOS + tid];
        float e2 = xeT[2 * XOS + tid], e3 = xeT[3 * XOS + tid];
        float e4 = xeT[4 * XOS + tid];
        uint4 u;
        u.x = packbf2(e0, e1); u.y = packbf2(e2, e3);
        u.z = packbf2(e4, 0.f); u.w = 0u;
        *(uint4*)&xe_out[(size_t)i * 8] = u;
    }

    // reduce: tid<160 owns (ch = tid>>5 in 0..4, chunk = tid&31 of 8 pts) -> short serial tail
    if (tid < 160) {
        int ch = tid >> 5, chunk = tid & 31;
        float racc = 0.f;
        int cur = sb[chunk * 8];
#pragma unroll
        for (int g = 0; g < 2; ++g) {
            float4 v4 = *(const float4*)&xeT[ch * XOS + chunk * 8 + g * 4];
            int4   n4 = *(const int4*)&sb[chunk * 8 + g * 4];
            float vv[4] = {v4.x, v4.y, v4.z, v4.w};
            int   nn[4] = {n4.x, n4.y, n4.z, n4.w};
#pragma unroll
            for (int k = 0; k < 4; ++k) {
                if (nn[k] != cur) {
                    if (cur >= 0) atomicAdd(&x_aggr[cur * 5 + ch], racc);
                    cur = nn[k];
                    racc = vv[k];
                } else {
                    racc += vv[k];
                }
            }
        }
        if (cur >= 0) atomicAdd(&x_aggr[cur * 5 + ch], racc);
    }
}

// ---------------- Pass B: per-graph global FFN + fold into W_out1 rows 5..8 ----------------
__global__ __launch_bounds__(256) void k_global(
    const float* __restrict__ x_aggr,
    const float* __restrict__ Wg1, const float* __restrict__ Wg2,
    const float* __restrict__ Wo1,
    float* __restrict__ g_contrib)
{
    __shared__ float sWg1[5 * HID];
    __shared__ float sWg2[HID * 4];
    __shared__ float sWo1g[4 * HID];
    for (int k = threadIdx.x; k < 5 * HID; k += 256) sWg1[k] = Wg1[k];
    for (int k = threadIdx.x; k < HID * 4; k += 256) sWg2[k] = Wg2[k];
    for (int k = threadIdx.x; k < 4 * HID; k += 256) sWo1g[k] = Wo1[5 * HID + k];
    __syncthreads();

    int bg = blockIdx.x * 256 + threadIdx.x;
    if (bg >= NUM_GRAPHS) return;

    float a[5];
#pragma unroll
    for (int c = 0; c < 5; ++c) a[c] = x_aggr[bg * 5 + c];

    float h[HID];
#pragma unroll
    for (int j = 0; j < HID; ++j) {
        float s = 0.f;
#pragma unroll
        for (int c = 0; c < 5; ++c) s += a[c] * sWg1[c * HID + j];
        h[j] = lrelu(s);
    }
    float g[4];
#pragma unroll
    for (int c = 0; c < 4; ++c) {
        float s = 0.f;
#pragma unroll
        for (int j = 0; j < HID; ++j) s += h[j] * sWg2[j * 4 + c];
        g[c] = lrelu(s);
    }
#pragma unroll
    for (int j = 0; j < HID; ++j) {
        float s = 0.f;
#pragma unroll
        for (int c = 0; c < 4; ++c) s += g[c] * sWo1g[c * HID + j];
        g_contrib[bg * HID + j] = s;
    }
}

// ---------------- Pass C: prefetched xe load, h1 VALU, 40x32 bf16 MFMA, two-half transpose-pool ----------------
// Two-half pool loop FULLY UNROLLED (R8 lesson: runtime-indexed xov -> scratch spill, 250 MB WRITE).
__global__ __launch_bounds__(256, 4) void k_out_pool(
    const float* __restrict__ x, const int* __restrict__ batch,
    const float* __restrict__ We1, const float* __restrict__ We2,
    const float* __restrict__ Wo1, const float* __restrict__ Wo2,
    const float* __restrict__ g_contrib,
    const unsigned short* __restrict__ xe_in, int use_xe,
    float* __restrict__ pooled)
{
    __shared__ __align__(16) unsigned int uLds[TILE * AROW];
    __shared__ __align__(16) int sb[TILE];
    __shared__ float sWe1[3 * HID];      // fallback path only
    __shared__ float sWe2T[5 * HID];     // fallback path only
    __shared__ float sWo1[5 * HID];

    int tid = threadIdx.x;
    for (int k = tid; k < 3 * HID; k += 256) sWe1[k] = We1[k];
    for (int k = tid; k < 5 * HID; k += 256) sWe2T[k] = We2[(k % HID) * 5 + k / HID];
    for (int k = tid; k < 5 * HID; k += 256) sWo1[k] = Wo1[k];

    int lane = tid & 63;
    int l16 = lane & 15, quad = lane >> 4;

    short8 bfrag[2][2];
#pragma unroll
    for (int nt = 0; nt < 2; ++nt) {
#pragma unroll
        for (int ks = 0; ks < 2; ++ks) {
#pragma unroll
            for (int j = 0; j < 8; ++j) {
                int kk = ks * 32 + quad * 8 + j;
                float w = (kk < HID) ? Wo2[kk * 32 + nt * 16 + l16] : 0.f;
                bfrag[nt][ks][j] = (short)f2bf(w);
            }
        }
    }
    short8 zfrag = {0, 0, 0, 0, 0, 0, 0, 0};
    __syncthreads();

    int t = blockIdx.x;
    int pb = -1;
    uint4 pxe = {0u, 0u, 0u, 0u};
    {
        int i = t * TILE + tid;
        bool v = i < N_POINTS;
        int ic = v ? i : (N_POINTS - 1);
        pb = v ? batch[ic] : -1;
        if (use_xe) pxe = *(const uint4*)&xe_in[(size_t)ic * 8];
    }

    for (; t < NTILES; t += GRID_C) {
        int i = t * TILE + tid;
        bool v = i < N_POINTS;
        int ic = v ? i : (N_POINTS - 1);
        int b = pb;
        uint4 xe4 = pxe;
        sb[tid] = b;

        int tn = t + GRID_C;
        if (tn < NTILES) {
            int i2 = tn * TILE + tid;
            bool v2 = i2 < N_POINTS;
            int ic2 = v2 ? i2 : (N_POINTS - 1);
            pb = v2 ? batch[ic2] : -1;
            if (use_xe) pxe = *(const uint4*)&xe_in[(size_t)ic2 * 8];
        }

        float xe[5];
        if (use_xe) {
            xe[0] = bflo(xe4.x); xe[1] = bfhi(xe4.x);
            xe[2] = bflo(xe4.y); xe[3] = bfhi(xe4.y);
            xe[4] = bflo(xe4.z);
        } else {
            float x0 = x[ic * 3 + 0], x1 = x[ic * 3 + 1], x2 = x[ic * 3 + 2];
            float h[HID];
            const float4* W1r = (const float4*)sWe1;
#pragma unroll
            for (int j4 = 0; j4 < HID / 4; ++j4) {
                float4 wa = W1r[j4], wb = W1r[10 + j4], wc = W1r[20 + j4];
                float wav[4] = {wa.x, wa.y, wa.z, wa.w};
                float wbv[4] = {wb.x, wb.y, wb.z, wb.w};
                float wcv[4] = {wc.x, wc.y, wc.z, wc.w};
#pragma unroll
                for (int k = 0; k < 4; ++k)
                    h[j4 * 4 + k] = lrelu(x0 * wav[k] + x1 * wbv[k] + x2 * wcv[k]);
            }
#pragma unroll
            for (int c = 0; c < 5; ++c) {
                const float4* wr = (const float4*)&sWe2T[c * HID];
                float s = 0.f;
#pragma unroll
                for (int j4 = 0; j4 < HID / 4; ++j4) {
                    float4 w = wr[j4];
                    s += h[j4 * 4 + 0] * w.x + h[j4 * 4 + 1] * w.y + h[j4 * 4 + 2] * w.z + h[j4 * 4 + 3] * w.w;
                }
                xe[c] = lrelu(s);
            }
        }

        const float4* gc4 = (const float4*)(g_contrib + (size_t)(v ? b : 0) * HID);
        unsigned int* row = &uLds[tid * AROW];
#pragma unroll
        for (int j4 = 0; j4 < HID / 4; ++j4) {
            float4 g = gc4[j4];
            float sv[4] = {g.x, g.y, g.z, g.w};
#pragma unroll
            for (int c = 0; c < 5; ++c) {
                float4 w = ((const float4*)&sWo1[c * HID])[j4];
                float wvv[4] = {w.x, w.y, w.z, w.w};
#pragma unroll
                for (int k = 0; k < 4; ++k) sv[k] += xe[c] * wvv[k];
            }
            uint2 u;
            u.x = packbf2(lrelu(sv[0]), lrelu(sv[1]));
            u.y = packbf2(lrelu(sv[2]), lrelu(sv[3]));
            *(uint2*)(row + j4 * 2) = u;
        }

        fx4 xov[4][2];
#pragma unroll
        for (int m = 0; m < 4; ++m) {
            int mt = (tid >> 6) * 4 + m;
            const unsigned int* arow = &uLds[(mt * 16 + l16) * AROW];
            short8 a0 = *(const short8*)(arow + quad * 4);
            short8 a1 = (quad == 0) ? *(const short8*)(arow + 16) : zfrag;
#pragma unroll
            for (int nt = 0; nt < 2; ++nt) {
                fx4 acc = {0.f, 0.f, 0.f, 0.f};
                acc = __builtin_amdgcn_mfma_f32_16x16x32_bf16(a0, bfrag[nt][0], acc, 0, 0, 0);
                acc = __builtin_amdgcn_mfma_f32_16x16x32_bf16(a1, bfrag[nt][1], acc, 0, 0, 0);
#pragma unroll
                for (int r = 0; r < 4; ++r) acc[r] = lrelu(acc[r]);
                xov[m][nt] = acc;
            }
        }
        __syncthreads();

        float* xoT = (float*)uLds;
#pragma unroll
        for (int half = 0; half < 2; ++half) {
#pragma unroll
            for (int m = 0; m < 4; ++m) {
                int mt = (tid >> 6) * 4 + m;
                int pt = mt * 16 + quad * 4;
                *(fx4*)&xoT[l16 * XOS + pt] = xov[m][half];
            }
            __syncthreads();

            if (tid < 128) {
                int ch = tid & 15, chunk = tid >> 4;
                float acc = 0.f;
                int cur = sb[chunk * 32];
#pragma unroll
                for (int g = 0; g < 8; ++g) {
                    float4 v4 = *(const float4*)&xoT[ch * XOS + chunk * 32 + g * 4];
                    int4   n4 = *(const int4*)&sb[chunk * 32 + g * 4];
                    float vv[4] = {v4.x, v4.y, v4.z, v4.w};
                    int   nn[4] = {n4.x, n4.y, n4.z, n4.w};
#pragma unroll
                    for (int k = 0; k < 4; ++k) {
                        if (nn[k] != cur) {
                            if (cur >= 0) atomicAdd(&pooled[cur * 32 + half * 16 + ch], acc);
                            cur = nn[k];
                            acc = vv[k];
                        } else {
                            acc += vv[k];
                        }
                    }
                }
                if (cur >= 0) atomicAdd(&pooled[cur * 32 + half * 16 + ch], acc);
            }
            __syncthreads();
        }
    }
}

// ---------------- Pass D: disc head per graph ----------------
__global__ __launch_bounds__(256) void k_disc(
    const float* __restrict__ pooled,
    const float* __restrict__ Wd1, const float* __restrict__ Wd2,
    float* __restrict__ out)
{
    __shared__ float sWd1T[HID * 32];  // [j][c]
    __shared__ float sWd2[HID];
    for (int k = threadIdx.x; k < 32 * HID; k += 256) sWd1T[k] = Wd1[(k % 32) * HID + k / 32];
    for (int k = threadIdx.x; k < HID; k += 256) sWd2[k] = Wd2[k];
    __syncthreads();

    int bg = blockIdx.x * 256 + threadIdx.x;
    if (bg >= NUM_GRAPHS) return;

    float p[32];
    const float4* pp = (const float4*)(pooled + (size_t)bg * 32);
#pragma unroll
    for (int c4 = 0; c4 < 8; ++c4) {
        float4 vv = pp[c4];
        p[c4 * 4 + 0] = vv.x; p[c4 * 4 + 1] = vv.y; p[c4 * 4 + 2] = vv.z; p[c4 * 4 + 3] = vv.w;
    }

    float acc = 0.f;
#pragma unroll
    for (int j = 0; j < HID; ++j) {
        const float4* wr = (const float4*)&sWd1T[j * 32];
        float s = 0.f;
#pragma unroll
        for (int c4 = 0; c4 < 8; ++c4) {
            float4 w = wr[c4];
            s += p[c4 * 4 + 0] * w.x + p[c4 * 4 + 1] * w.y + p[c4 * 4 + 2] * w.z + p[c4 * 4 + 3] * w.w;
        }
        acc += lrelu(s) * sWd2[j];
    }
    out[bg] = acc;
}

extern "C" void kernel_launch(void* const* d_in, const int* in_sizes, int n_in,
                              void* d_out, int out_size, void* d_ws, size_t ws_size,
                              hipStream_t stream) {
    const float* x     = (const float*)d_in[0];
    const int*   batch = (const int*)  d_in[1];
    const float* We1   = (const float*)d_in[2];
    const float* We2   = (const float*)d_in[3];
    const float* Wg1   = (const float*)d_in[4];
    const float* Wg2   = (const float*)d_in[5];
    const float* Wo1   = (const float*)d_in[6];
    const float* Wo2   = (const float*)d_in[7];
    const float* Wd1   = (const float*)d_in[8];
    const float* Wd2   = (const float*)d_in[9];
    float* out = (float*)d_out;

    // ws layout: [x_aggr B*5][pooled B*32][g_contrib B*40][xe bf16 interleaved N*8]
    float* x_aggr    = (float*)d_ws;
    float* pooled    = x_aggr + NUM_GRAPHS * 5;
    float* g_contrib = pooled + NUM_GRAPHS * 32;
    size_t head_bytes = (size_t)NUM_GRAPHS * (5 + 32 + HID) * sizeof(float);
    unsigned short* xe_ws = (unsigned short*)((char*)d_ws + head_bytes);
    size_t need = head_bytes + (size_t)N_POINTS * 8 * sizeof(unsigned short);
    int use_xe = (ws_size >= need) ? 1 : 0;

    hipMemsetAsync(d_ws, 0, (size_t)NUM_GRAPHS * (5 + 32) * sizeof(float), stream);

    int gblk = (NUM_GRAPHS + 255) / 256;
    k_emb_aggr<<<NT_E, 256, 0, stream>>>(x, batch, We1, We2, x_aggr, xe_ws, use_xe);
    k_global <<<gblk, 256, 0, stream>>>(x_aggr, Wg1, Wg2, Wo1, g_contrib);
    k_out_pool<<<GRID_C, 256, 0, stream>>>(x, batch, We1, We2, Wo1, Wo2, g_contrib,
                                           xe_ws, use_xe, pooled);
    k_disc   <<<gblk, 256, 0, stream>>>(pooled, Wd1, Wd2, out);
}

// Round 11
// 274.554 us; speedup vs baseline: 1.2140x; 1.0035x over previous
//
#include <hip/hip_runtime.h>
#include <hip/hip_bf16.h>

#define N_POINTS   2000000
#define NUM_GRAPHS 16384
#define HID        40
#define SLOPE      0.01f

// Pass A (emb): 256 pts/block, 1 pt/thread, MFMA layer2
#define TILE_E     256
#define NT_E       ((N_POINTS + TILE_E - 1) / TILE_E)   // 7813

// Pass C tiling: 256 pts/tile, grid-stride
#define TILE       256
#define NTILES     ((N_POINTS + TILE - 1) / TILE)       // 7813
#define AROW       20     // dwords per bf16 A-staging row (40 bf16)
#define XOS        260    // dwords per xoT/xeT channel row (%32==4, 16B aligned)
#define GRID_C     1536

typedef __attribute__((ext_vector_type(8))) short short8;
typedef __attribute__((ext_vector_type(4))) float fx4;

__device__ __forceinline__ float lrelu(float v) { return v > 0.f ? v : SLOPE * v; }
__device__ __forceinline__ unsigned short f2bf(float f) {
    __hip_bfloat16 h = __float2bfloat16(f);
    return *(unsigned short*)&h;
}
__device__ __forceinline__ unsigned int packbf2(float a, float b) {
    __hip_bfloat162 p = __float22bfloat162_rn(make_float2(a, b));
    return *(unsigned int*)&p;
}
__device__ __forceinline__ float bflo(unsigned int d) { return __uint_as_float(d << 16); }
__device__ __forceinline__ float bfhi(unsigned int d) { return __uint_as_float(d & 0xffff0000u); }

// ---------------- Pass A: emb layer1 VALU (packed bf16), layer2 MFMA, xeT reduce + cache ----------------
// launch_bounds(256,4): R10 lesson — with NO min-waves arg the allocator chose VGPR=40 and
// spilled ~4 dwords/thread (WRITE_SIZE 66 MB vs 33 expected). Budget must be stated: 4 waves/EU
// -> <=128 VGPR, need ~70. (R7 lesson: too-tight bounds ALSO spill. State exactly what's needed.)
__global__ __launch_bounds__(256, 4) void k_emb_aggr(
    const float* __restrict__ x, const int* __restrict__ batch,
    const float* __restrict__ We1, const float* __restrict__ We2,
    float* __restrict__ x_aggr, unsigned short* __restrict__ xe_out, int use_xe)
{
    // A-staging (256 x 20 dw = 20480 B) aliased (after barrier) with xeT (5 x 260 dw = 5200 B)
    __shared__ __align__(16) unsigned int uLds[TILE_E * AROW];
    __shared__ __align__(16) int sb[TILE_E];
    __shared__ __align__(16) float sWe1[3 * HID];

    int tid = threadIdx.x;
    for (int k = tid; k < 3 * HID; k += 256) sWe1[k] = We1[k];

    int lane = tid & 63;
    int l16 = lane & 15, quad = lane >> 4;

    // B fragments for layer2: B[k][n] = We2[k*5+n]; lane n=l16 (valid n<5), k=ks*32+quad*8+j
    short8 bfrag[2];
#pragma unroll
    for (int ks = 0; ks < 2; ++ks) {
#pragma unroll
        for (int j = 0; j < 8; ++j) {
            int kk = ks * 32 + quad * 8 + j;
            float w = (kk < HID && l16 < 5) ? We2[kk * 5 + l16] : 0.f;
            bfrag[ks][j] = (short)f2bf(w);
        }
    }
    short8 zfrag = {0, 0, 0, 0, 0, 0, 0, 0};
    __syncthreads();

    int i = blockIdx.x * TILE_E + tid;
    bool v = i < N_POINTS;
    int ic = v ? i : (N_POINTS - 1);
    float x0 = x[ic * 3 + 0], x1 = x[ic * 3 + 1], x2 = x[ic * 3 + 2];
    int b = v ? batch[ic] : -1;
    sb[tid] = b;

    // layer1: h = lrelu(x @ We1), packed to bf16 pairs as computed (20 u32 of state)
    unsigned int hpk[2 * (HID / 4)];
    const float4* W1r = (const float4*)sWe1;
#pragma unroll
    for (int j4 = 0; j4 < HID / 4; ++j4) {
        float4 wa = W1r[j4], wb = W1r[10 + j4], wc = W1r[20 + j4];
        float hv0 = lrelu(x0 * wa.x + x1 * wb.x + x2 * wc.x);
        float hv1 = lrelu(x0 * wa.y + x1 * wb.y + x2 * wc.y);
        float hv2 = lrelu(x0 * wa.z + x1 * wb.z + x2 * wc.z);
        float hv3 = lrelu(x0 * wa.w + x1 * wb.w + x2 * wc.w);
        hpk[j4 * 2 + 0] = packbf2(hv0, hv1);
        hpk[j4 * 2 + 1] = packbf2(hv2, hv3);
    }

    // stage A row (wave-private rows: wave w stages tids 64w..64w+63, reads mtiles 4w..4w+3)
    unsigned int* row = &uLds[tid * AROW];
#pragma unroll
    for (int j4 = 0; j4 < HID / 4; ++j4) {
        uint2 u;
        u.x = hpk[j4 * 2 + 0];
        u.y = hpk[j4 * 2 + 1];
        *(uint2*)(row + j4 * 2) = u;
    }

    // MFMA layer2: wave owns mtiles 4w..4w+3; 1 ntile (5 of 16 cols used); K=32+8
    fx4 acc[4];
#pragma unroll
    for (int m = 0; m < 4; ++m) {
        int mt = (tid >> 6) * 4 + m;
        const unsigned int* arow = &uLds[(mt * 16 + l16) * AROW];
        short8 a0 = *(const short8*)(arow + quad * 4);
        short8 a1 = (quad == 0) ? *(const short8*)(arow + 16) : zfrag;
        fx4 c = {0.f, 0.f, 0.f, 0.f};
        c = __builtin_amdgcn_mfma_f32_16x16x32_bf16(a0, bfrag[0], c, 0, 0, 0);
        c = __builtin_amdgcn_mfma_f32_16x16x32_bf16(a1, bfrag[1], c, 0, 0, 0);
#pragma unroll
        for (int r = 0; r < 4; ++r) c[r] = lrelu(c[r]);
        acc[m] = c;
    }
    __syncthreads();   // all A-reads done -> safe to clobber staging with xeT

    // C layout: col=l16=channel (<5 valid), row=quad*4+r=pt -> fx4 of 4 consecutive pts
    float* xeT = (float*)uLds;
    if (l16 < 5) {
#pragma unroll
        for (int m = 0; m < 4; ++m) {
            int mt = (tid >> 6) * 4 + m;
            *(fx4*)&xeT[l16 * XOS + mt * 16 + quad * 4] = acc[m];
        }
    }
    __syncthreads();

    // interleaved bf16 xe cache: one uint4 store per point
    if (use_xe && v) {
        float e0 = xeT[0 * XOS + tid], e1 = xeT[1 * XOS + tid];
        float e2 = xeT[2 * XOS + tid], e3 = xeT[3 * XOS + tid];
        float e4 = xeT[4 * XOS + tid];
        uint4 u;
        u.x = packbf2(e0, e1); u.y = packbf2(e2, e3);
        u.z = packbf2(e4, 0.f); u.w = 0u;
        *(uint4*)&xe_out[(size_t)i * 8] = u;
    }

    // reduce: tid<160 owns (ch = tid>>5 in 0..4, chunk = tid&31 of 8 pts) -> short serial tail
    if (tid < 160) {
        int ch = tid >> 5, chunk = tid & 31;
        float racc = 0.f;
        int cur = sb[chunk * 8];
#pragma unroll
        for (int g = 0; g < 2; ++g) {
            float4 v4 = *(const float4*)&xeT[ch * XOS + chunk * 8 + g * 4];
            int4   n4 = *(const int4*)&sb[chunk * 8 + g * 4];
            float vv[4] = {v4.x, v4.y, v4.z, v4.w};
            int   nn[4] = {n4.x, n4.y, n4.z, n4.w};
#pragma unroll
            for (int k = 0; k < 4; ++k) {
                if (nn[k] != cur) {
                    if (cur >= 0) atomicAdd(&x_aggr[cur * 5 + ch], racc);
                    cur = nn[k];
                    racc = vv[k];
                } else {
                    racc += vv[k];
                }
            }
        }
        if (cur >= 0) atomicAdd(&x_aggr[cur * 5 + ch], racc);
    }
}

// ---------------- Pass B: per-graph global FFN + fold into W_out1 rows 5..8 ----------------
__global__ __launch_bounds__(256) void k_global(
    const float* __restrict__ x_aggr,
    const float* __restrict__ Wg1, const float* __restrict__ Wg2,
    const float* __restrict__ Wo1,
    float* __restrict__ g_contrib)
{
    __shared__ float sWg1[5 * HID];
    __shared__ float sWg2[HID * 4];
    __shared__ float sWo1g[4 * HID];
    for (int k = threadIdx.x; k < 5 * HID; k += 256) sWg1[k] = Wg1[k];
    for (int k = threadIdx.x; k < HID * 4; k += 256) sWg2[k] = Wg2[k];
    for (int k = threadIdx.x; k < 4 * HID; k += 256) sWo1g[k] = Wo1[5 * HID + k];
    __syncthreads();

    int bg = blockIdx.x * 256 + threadIdx.x;
    if (bg >= NUM_GRAPHS) return;

    float a[5];
#pragma unroll
    for (int c = 0; c < 5; ++c) a[c] = x_aggr[bg * 5 + c];

    float h[HID];
#pragma unroll
    for (int j = 0; j < HID; ++j) {
        float s = 0.f;
#pragma unroll
        for (int c = 0; c < 5; ++c) s += a[c] * sWg1[c * HID + j];
        h[j] = lrelu(s);
    }
    float g[4];
#pragma unroll
    for (int c = 0; c < 4; ++c) {
        float s = 0.f;
#pragma unroll
        for (int j = 0; j < HID; ++j) s += h[j] * sWg2[j * 4 + c];
        g[c] = lrelu(s);
    }
#pragma unroll
    for (int j = 0; j < HID; ++j) {
        float s = 0.f;
#pragma unroll
        for (int c = 0; c < 4; ++c) s += g[c] * sWo1g[c * HID + j];
        g_contrib[bg * HID + j] = s;
    }
}

// ---------------- Pass C: prefetched xe load, h1 VALU, 40x32 bf16 MFMA, two-half transpose-pool ----------------
// Two-half pool loop FULLY UNROLLED (R8 lesson: runtime-indexed xov -> scratch spill, 250 MB WRITE).
__global__ __launch_bounds__(256, 4) void k_out_pool(
    const float* __restrict__ x, const int* __restrict__ batch,
    const float* __restrict__ We1, const float* __restrict__ We2,
    const float* __restrict__ Wo1, const float* __restrict__ Wo2,
    const float* __restrict__ g_contrib,
    const unsigned short* __restrict__ xe_in, int use_xe,
    float* __restrict__ pooled)
{
    __shared__ __align__(16) unsigned int uLds[TILE * AROW];
    __shared__ __align__(16) int sb[TILE];
    __shared__ float sWe1[3 * HID];      // fallback path only
    __shared__ float sWe2T[5 * HID];     // fallback path only
    __shared__ float sWo1[5 * HID];

    int tid = threadIdx.x;
    for (int k = tid; k < 3 * HID; k += 256) sWe1[k] = We1[k];
    for (int k = tid; k < 5 * HID; k += 256) sWe2T[k] = We2[(k % HID) * 5 + k / HID];
    for (int k = tid; k < 5 * HID; k += 256) sWo1[k] = Wo1[k];

    int lane = tid & 63;
    int l16 = lane & 15, quad = lane >> 4;

    short8 bfrag[2][2];
#pragma unroll
    for (int nt = 0; nt < 2; ++nt) {
#pragma unroll
        for (int ks = 0; ks < 2; ++ks) {
#pragma unroll
            for (int j = 0; j < 8; ++j) {
                int kk = ks * 32 + quad * 8 + j;
                float w = (kk < HID) ? Wo2[kk * 32 + nt * 16 + l16] : 0.f;
                bfrag[nt][ks][j] = (short)f2bf(w);
            }
        }
    }
    short8 zfrag = {0, 0, 0, 0, 0, 0, 0, 0};
    __syncthreads();

    int t = blockIdx.x;
    int pb = -1;
    uint4 pxe = {0u, 0u, 0u, 0u};
    {
        int i = t * TILE + tid;
        bool v = i < N_POINTS;
        int ic = v ? i : (N_POINTS - 1);
        pb = v ? batch[ic] : -1;
        if (use_xe) pxe = *(const uint4*)&xe_in[(size_t)ic * 8];
    }

    for (; t < NTILES; t += GRID_C) {
        int i = t * TILE + tid;
        bool v = i < N_POINTS;
        int ic = v ? i : (N_POINTS - 1);
        int b = pb;
        uint4 xe4 = pxe;
        sb[tid] = b;

        int tn = t + GRID_C;
        if (tn < NTILES) {
            int i2 = tn * TILE + tid;
            bool v2 = i2 < N_POINTS;
            int ic2 = v2 ? i2 : (N_POINTS - 1);
            pb = v2 ? batch[ic2] : -1;
            if (use_xe) pxe = *(const uint4*)&xe_in[(size_t)ic2 * 8];
        }

        float xe[5];
        if (use_xe) {
            xe[0] = bflo(xe4.x); xe[1] = bfhi(xe4.x);
            xe[2] = bflo(xe4.y); xe[3] = bfhi(xe4.y);
            xe[4] = bflo(xe4.z);
        } else {
            float x0 = x[ic * 3 + 0], x1 = x[ic * 3 + 1], x2 = x[ic * 3 + 2];
            float h[HID];
            const float4* W1r = (const float4*)sWe1;
#pragma unroll
            for (int j4 = 0; j4 < HID / 4; ++j4) {
                float4 wa = W1r[j4], wb = W1r[10 + j4], wc = W1r[20 + j4];
                float wav[4] = {wa.x, wa.y, wa.z, wa.w};
                float wbv[4] = {wb.x, wb.y, wb.z, wb.w};
                float wcv[4] = {wc.x, wc.y, wc.z, wc.w};
#pragma unroll
                for (int k = 0; k < 4; ++k)
                    h[j4 * 4 + k] = lrelu(x0 * wav[k] + x1 * wbv[k] + x2 * wcv[k]);
            }
#pragma unroll
            for (int c = 0; c < 5; ++c) {
                const float4* wr = (const float4*)&sWe2T[c * HID];
                float s = 0.f;
#pragma unroll
                for (int j4 = 0; j4 < HID / 4; ++j4) {
                    float4 w = wr[j4];
                    s += h[j4 * 4 + 0] * w.x + h[j4 * 4 + 1] * w.y + h[j4 * 4 + 2] * w.z + h[j4 * 4 + 3] * w.w;
                }
                xe[c] = lrelu(s);
            }
        }

        const float4* gc4 = (const float4*)(g_contrib + (size_t)(v ? b : 0) * HID);
        unsigned int* row = &uLds[tid * AROW];
#pragma unroll
        for (int j4 = 0; j4 < HID / 4; ++j4) {
            float4 g = gc4[j4];
            float sv[4] = {g.x, g.y, g.z, g.w};
#pragma unroll
            for (int c = 0; c < 5; ++c) {
                float4 w = ((const float4*)&sWo1[c * HID])[j4];
                float wvv[4] = {w.x, w.y, w.z, w.w};
#pragma unroll
                for (int k = 0; k < 4; ++k) sv[k] += xe[c] * wvv[k];
            }
            uint2 u;
            u.x = packbf2(lrelu(sv[0]), lrelu(sv[1]));
            u.y = packbf2(lrelu(sv[2]), lrelu(sv[3]));
            *(uint2*)(row + j4 * 2) = u;
        }

        fx4 xov[4][2];
#pragma unroll
        for (int m = 0; m < 4; ++m) {
            int mt = (tid >> 6) * 4 + m;
            const unsigned int* arow = &uLds[(mt * 16 + l16) * AROW];
            short8 a0 = *(const short8*)(arow + quad * 4);
            short8 a1 = (quad == 0) ? *(const short8*)(arow + 16) : zfrag;
#pragma unroll
            for (int nt = 0; nt < 2; ++nt) {
                fx4 acc = {0.f, 0.f, 0.f, 0.f};
                acc = __builtin_amdgcn_mfma_f32_16x16x32_bf16(a0, bfrag[nt][0], acc, 0, 0, 0);
                acc = __builtin_amdgcn_mfma_f32_16x16x32_bf16(a1, bfrag[nt][1], acc, 0, 0, 0);
#pragma unroll
                for (int r = 0; r < 4; ++r) acc[r] = lrelu(acc[r]);
                xov[m][nt] = acc;
            }
        }
        __syncthreads();

        float* xoT = (float*)uLds;
#pragma unroll
        for (int half = 0; half < 2; ++half) {
#pragma unroll
            for (int m = 0; m < 4; ++m) {
                int mt = (tid >> 6) * 4 + m;
                int pt = mt * 16 + quad * 4;
                *(fx4*)&xoT[l16 * XOS + pt] = xov[m][half];
            }
            __syncthreads();

            if (tid < 128) {
                int ch = tid & 15, chunk = tid >> 4;
                float acc = 0.f;
                int cur = sb[chunk * 32];
#pragma unroll
                for (int g = 0; g < 8; ++g) {
                    float4 v4 = *(const float4*)&xoT[ch * XOS + chunk * 32 + g * 4];
                    int4   n4 = *(const int4*)&sb[chunk * 32 + g * 4];
                    float vv[4] = {v4.x, v4.y, v4.z, v4.w};
                    int   nn[4] = {n4.x, n4.y, n4.z, n4.w};
#pragma unroll
                    for (int k = 0; k < 4; ++k) {
                        if (nn[k] != cur) {
                            if (cur >= 0) atomicAdd(&pooled[cur * 32 + half * 16 + ch], acc);
                            cur = nn[k];
                            acc = vv[k];
                        } else {
                            acc += vv[k];
                        }
                    }
                }
                if (cur >= 0) atomicAdd(&pooled[cur * 32 + half * 16 + ch], acc);
            }
            __syncthreads();
        }
    }
}

// ---------------- Pass D: disc head per graph ----------------
__global__ __launch_bounds__(256) void k_disc(
    const float* __restrict__ pooled,
    const float* __restrict__ Wd1, const float* __restrict__ Wd2,
    float* __restrict__ out)
{
    __shared__ float sWd1T[HID * 32];  // [j][c]
    __shared__ float sWd2[HID];
    for (int k = threadIdx.x; k < 32 * HID; k += 256) sWd1T[k] = Wd1[(k % 32) * HID + k / 32];
    for (int k = threadIdx.x; k < HID; k += 256) sWd2[k] = Wd2[k];
    __syncthreads();

    int bg = blockIdx.x * 256 + threadIdx.x;
    if (bg >= NUM_GRAPHS) return;

    float p[32];
    const float4* pp = (const float4*)(pooled + (size_t)bg * 32);
#pragma unroll
    for (int c4 = 0; c4 < 8; ++c4) {
        float4 vv = pp[c4];
        p[c4 * 4 + 0] = vv.x; p[c4 * 4 + 1] = vv.y; p[c4 * 4 + 2] = vv.z; p[c4 * 4 + 3] = vv.w;
    }

    float acc = 0.f;
#pragma unroll
    for (int j = 0; j < HID; ++j) {
        const float4* wr = (const float4*)&sWd1T[j * 32];
        float s = 0.f;
#pragma unroll
        for (int c4 = 0; c4 < 8; ++c4) {
            float4 w = wr[c4];
            s += p[c4 * 4 + 0] * w.x + p[c4 * 4 + 1] * w.y + p[c4 * 4 + 2] * w.z + p[c4 * 4 + 3] * w.w;
        }
        acc += lrelu(s) * sWd2[j];
    }
    out[bg] = acc;
}

extern "C" void kernel_launch(void* const* d_in, const int* in_sizes, int n_in,
                              void* d_out, int out_size, void* d_ws, size_t ws_size,
                              hipStream_t stream) {
    const float* x     = (const float*)d_in[0];
    const int*   batch = (const int*)  d_in[1];
    const float* We1   = (const float*)d_in[2];
    const float* We2   = (const float*)d_in[3];
    const float* Wg1   = (const float*)d_in[4];
    const float* Wg2   = (const float*)d_in[5];
    const float* Wo1   = (const float*)d_in[6];
    const float* Wo2   = (const float*)d_in[7];
    const float* Wd1   = (const float*)d_in[8];
    const float* Wd2   = (const float*)d_in[9];
    float* out = (float*)d_out;

    // ws layout: [x_aggr B*5][pooled B*32][g_contrib B*40][xe bf16 interleaved N*8]
    float* x_aggr    = (float*)d_ws;
    float* pooled    = x_aggr + NUM_GRAPHS * 5;
    float* g_contrib = pooled + NUM_GRAPHS * 32;
    size_t head_bytes = (size_t)NUM_GRAPHS * (5 + 32 + HID) * sizeof(float);
    unsigned short* xe_ws = (unsigned short*)((char*)d_ws + head_bytes);
    size_t need = head_bytes + (size_t)N_POINTS * 8 * sizeof(unsigned short);
    int use_xe = (ws_size >= need) ? 1 : 0;

    hipMemsetAsync(d_ws, 0, (size_t)NUM_GRAPHS * (5 + 32) * sizeof(float), stream);

    int gblk = (NUM_GRAPHS + 255) / 256;
    k_emb_aggr<<<NT_E, 256, 0, stream>>>(x, batch, We1, We2, x_aggr, xe_ws, use_xe);
    k_global <<<gblk, 256, 0, stream>>>(x_aggr, Wg1, Wg2, Wo1, g_contrib);
    k_out_pool<<<GRID_C, 256, 0, stream>>>(x, batch, We1, We2, Wo1, Wo2, g_contrib,
                                           xe_ws, use_xe, pooled);
    k_disc   <<<gblk, 256, 0, stream>>>(pooled, Wd1, Wd2, out);
}